// Round 1
// baseline (973.782 us; speedup 1.0000x reference)
//
#include <hip/hip_runtime.h>
#include <math.h>

// Problem constants
#define Bn 32
#define Sn 2048
#define Hn 512
#define En 512
#define Mn (Bn*Sn)       // 65536 flattened [B*S] rows
#define CH 128           // s-rows per GEMM m-block == cumsum chunk size
#define NCH (Sn/CH)      // 16 chunks per batch
#define NBLK (En/128)    // 4 n-blocks
#define NG (Bn*NBLK)     // 128 chain groups (b x nblk)
#define BK 64            // GEMM K-tile
#define NT (Hn/BK)       // 8 K-steps
#define NBLOCKS (Bn*NCH*NBLK)   // 2048

using short8  = __attribute__((ext_vector_type(8))) short;   // 8 bf16 MFMA A/B frag
using floatx4 = __attribute__((ext_vector_type(4))) float;   // MFMA C/D frag

__device__ __forceinline__ unsigned short f2bf(float x) {
    unsigned u = __float_as_uint(x);
    u += 0x7FFFu + ((u >> 16) & 1u);   // RNE
    return (unsigned short)(u >> 16);
}

// pack 2 f32 -> 2 bf16 (RNE), identical rounding to f2bf
__device__ __forceinline__ unsigned cvt_pk_bf16(float lo, float hi) {
    unsigned r;
    asm("v_cvt_pk_bf16_f32 %0, %1, %2" : "=v"(r) : "v"(lo), "v"(hi));
    return r;
}

__device__ __forceinline__ float fast_tanh(float x) {
    x = fminf(20.f, fmaxf(-20.f, x));
    float e = __expf(2.f * x);
    return (e - 1.f) * __builtin_amdgcn_rcpf(e + 1.f);
}

// async 16B/lane global->LDS: LDS dest is wave-uniform base + lane*16 (m104/m108)
__device__ __forceinline__ void load_lds16(const unsigned short* g, unsigned short* l) {
    __builtin_amdgcn_global_load_lds((const __attribute__((address_space(1))) void*)g,
                                     (__attribute__((address_space(3))) void*)l,
                                     16, 0, 0);
}

// ---------------------------------------------------------------------------
// K0: fp32 -> bf16 bulk convert (Wb only now). 8 elems/thread.
// ---------------------------------------------------------------------------
__global__ __launch_bounds__(256) void k_conv(const float* __restrict__ in,
                                              unsigned short* __restrict__ out, int n8) {
    int i = blockIdx.x * 256 + threadIdx.x;
    if (i >= n8) return;
    const float4 a = ((const float4*)in)[2*i];
    const float4 b = ((const float4*)in)[2*i + 1];
    short8 o;
    o[0]=f2bf(a.x); o[1]=f2bf(a.y); o[2]=f2bf(a.z); o[3]=f2bf(a.w);
    o[4]=f2bf(b.x); o[5]=f2bf(b.y); o[6]=f2bf(b.z); o[7]=f2bf(b.w);
    ((short8*)out)[i] = o;
}

// ---------------------------------------------------------------------------
// K_init: zero chain status flags + ticket counter (2049 words)
// ---------------------------------------------------------------------------
__global__ __launch_bounds__(256) void k_init(unsigned* __restrict__ p, int n) {
    int i = blockIdx.x * 256 + threadIdx.x;
    if (i < n) p[i] = 0u;
}

// ---------------------------------------------------------------------------
// K1: w[row] = exp(dot(alpha[row,:], Wa) + ba)   one wave per row
// ---------------------------------------------------------------------------
__global__ __launch_bounds__(256) void k_w(const float* __restrict__ alpha,
                                           const float* __restrict__ Wa,
                                           const float* __restrict__ ba,
                                           float* __restrict__ wout) {
    const int lane = threadIdx.x & 63;
    const int wq   = threadIdx.x >> 6;
    const int row  = blockIdx.x * 4 + wq;
    const float* ap = alpha + (size_t)row * Hn + lane * 8;
    const float* wp = Wa + lane * 8;
    float4 a0 = *(const float4*)ap;
    float4 a1 = *(const float4*)(ap + 4);
    float4 w0 = *(const float4*)wp;
    float4 w1 = *(const float4*)(wp + 4);
    float s = a0.x*w0.x + a0.y*w0.y + a0.z*w0.z + a0.w*w0.w
            + a1.x*w1.x + a1.y*w1.y + a1.z*w1.z + a1.w*w1.w;
    #pragma unroll
    for (int off = 32; off; off >>= 1) s += __shfl_down(s, off, 64);
    if (lane == 0) wout[row] = expf(s + ba[0]);
}

// ---------------------------------------------------------------------------
// K2: cw[b,:] = inclusive cumsum_s(w[b,:])   one wave per b (tiny)
// ---------------------------------------------------------------------------
__global__ __launch_bounds__(64) void k_scan_w(const float* __restrict__ w,
                                               float* __restrict__ cw) {
    const int b = blockIdx.x;
    const int lane = threadIdx.x;
    const float* wp = w  + (size_t)b * Sn;
    float*       cp = cw + (size_t)b * Sn;
    float carry = 0.f;
    for (int c = 0; c < Sn; c += 64) {
        float v = wp[c + lane];
        #pragma unroll
        for (int off = 1; off < 64; off <<= 1) {
            float t = __shfl_up(v, off, 64);
            if (lane >= off) v += t;
        }
        float o = carry + v;
        cp[c + lane] = o;
        carry = __shfl(o, 63, 64);
    }
}

// ---------------------------------------------------------------------------
// K3 (fused): t = w*tanh(beta@Wb^T + bb)*embed, within-chunk cumsum, cross-
// chunk chain (decoupled sequential scan), divide by cw, single write of out.
//  - 2-phase pipelined main loop (T3-min): stage(t+1) issued before compute(t)
//  - A reg-staged fp32->bf16 (kills the 201MB convert pass); B global_load_lds
//  - row-parity XOR swizzle on both LDS tiles (b128 bank-conflict floor);
//    B swizzled via pre-swizzled GLOBAL source (m173), A via ds_write addr
//  - tickets (chunk-major) make the chain deadlock-free: a block's
//    predecessor always holds a smaller ticket => scheduled earlier.
// ---------------------------------------------------------------------------
__global__ __launch_bounds__(256, 2) void k_gemm3(
        const float* __restrict__ Af,            // beta fp32 [Mn][Hn]
        const unsigned short* __restrict__ Bbf,  // Wb bf16 [En][Hn]
        const float* __restrict__ bbias,
        const float* __restrict__ wv,
        const float* __restrict__ cw,
        const float* __restrict__ embed,
        float* __restrict__ outp,
        float* __restrict__ incb,                // [NG*NCH][128] inclusive chunk prefixes
        unsigned* __restrict__ status,           // [NG*NCH] chain flags
        unsigned* __restrict__ counter)          // ticket
{
    __shared__ char  smem[65536];    // 2 x (A 16KB + B 16KB) double-buffered staging
    __shared__ float redbuf[256];    // per-wave column sums
    __shared__ float offsbuf[128];   // chain offsets (prior-chunk prefix) per column
    __shared__ int   sticket;

    const int tid  = threadIdx.x;
    const int lane = tid & 63, wq = tid >> 6;
    const int wave_n = wq & 1, wave_m = wq >> 1;   // 2x2 wave grid, 64x64 per wave
    const int lrow = lane & 15, quad = lane >> 4;

    if (tid == 0) sticket = (int)atomicAdd(counter, 1u);
    __syncthreads();
    const int ticket = sticket & (NBLOCKS - 1);
    const int cidx   = ticket >> 7;              // chunk (chunk-major => safe chain)
    const int g      = ticket & (NG - 1);
    const int bidx   = g >> 2;
    const int nblk   = g & (NBLK - 1);
    const int blockM = bidx * Sn + cidx * CH;
    const int blockN = nblk * 128;

    // staging geometry: 8 rows x 64 cols per instr-group; row parity = lane>>3
    const int srow = wq * 32 + (lane >> 3);
    const int swz8 = (lane >> 3) << 3;           // row-parity XOR, bf16-element units
    const int scol = (lane & 7) * 8;
    const float*          Ag = Af  + (size_t)(blockM + srow) * Hn + scol;
    const unsigned short* Bg = Bbf + (size_t)(blockN + srow) * Hn + (scol ^ swz8);

    floatx4 acc[4][4];
    #pragma unroll
    for (int i = 0; i < 4; i++)
        #pragma unroll
        for (int j = 0; j < 4; j++) acc[i][j] = (floatx4){0.f, 0.f, 0.f, 0.f};

    float4 areg[8];

    auto loadA = [&](int k0) {
        #pragma unroll
        for (int it = 0; it < 4; it++) {
            const float* p = Ag + (size_t)(it * 8) * Hn + k0;
            areg[2*it]     = *(const float4*)p;
            areg[2*it + 1] = *(const float4*)(p + 4);
        }
    };
    auto stageB = [&](int buf, int k0) {
        unsigned short* lb = (unsigned short*)(smem + buf * 32768 + 16384) + (wq * 32) * BK;
        #pragma unroll
        for (int it = 0; it < 4; it++)
            load_lds16(Bg + (size_t)(it * 8) * Hn + k0, lb + it * 8 * BK);
    };
    auto writeA = [&](int buf) {
        // lane*8 = (lane>>3)*BK + (lane&7)*8 ; XOR only touches the col bits
        unsigned short* la = (unsigned short*)(smem + buf * 32768)
                           + (wq * 32) * BK + ((lane * 8) ^ swz8);
        #pragma unroll
        for (int it = 0; it < 4; it++) {
            const float4 a = areg[2*it], b = areg[2*it + 1];
            uint4 o;
            o.x = cvt_pk_bf16(a.x, a.y);
            o.y = cvt_pk_bf16(a.z, a.w);
            o.z = cvt_pk_bf16(b.x, b.y);
            o.w = cvt_pk_bf16(b.z, b.w);
            *(uint4*)(la + it * 8 * BK) = o;
        }
    };
    auto compute = [&](int buf) {
        const unsigned short* la = (const unsigned short*)(smem + buf * 32768);
        const unsigned short* lb = (const unsigned short*)(smem + buf * 32768 + 16384);
        const int swzr = (lrow & 7) << 3;
        #pragma unroll
        for (int kk = 0; kk < BK; kk += 32) {
            short8 afr[4], bfr[4];
            #pragma unroll
            for (int j = 0; j < 4; j++)
                bfr[j] = *(const short8*)&lb[(wave_n*64 + j*16 + lrow)*BK + ((kk + quad*8) ^ swzr)];
            #pragma unroll
            for (int i = 0; i < 4; i++)
                afr[i] = *(const short8*)&la[(wave_m*64 + i*16 + lrow)*BK + ((kk + quad*8) ^ swzr)];
            #pragma unroll
            for (int i = 0; i < 4; i++)
                #pragma unroll
                for (int j = 0; j < 4; j++)
                    acc[i][j] = __builtin_amdgcn_mfma_f32_16x16x32_bf16(afr[i], bfr[j], acc[i][j], 0, 0, 0);
        }
    };

    // ---- 2-phase pipelined main loop: prefetch(t+1) issued before compute(t)
    loadA(0);
    stageB(0, 0);
    writeA(0);
    __syncthreads();
    #pragma unroll
    for (int t = 0; t < NT - 1; ++t) {
        const int cur = t & 1;
        loadA((t + 1) * BK);          // A fp32 loads for next tile, in flight...
        stageB(cur ^ 1, (t + 1) * BK);// ...B direct-to-LDS for next tile, in flight...
        compute(cur);                 // ...under the MFMAs of the current tile
        writeA(cur ^ 1);              // vmcnt-wait A regs, cvt, ds_write
        __syncthreads();              // one barrier per K-step
    }
    compute((NT - 1) & 1);
    // epilogue uses separate LDS arrays; no staging reuse -> no barrier needed here

    // ---- t-transform in registers: acc <- w * tanh(acc + bb) * embed ----
    const float* wvp = wv + blockM;
    const float* cwp = cw + blockM;
    float wr[4][4];
    #pragma unroll
    for (int i = 0; i < 4; i++)
        #pragma unroll
        for (int reg = 0; reg < 4; reg++)
            wr[i][reg] = wvp[wave_m*64 + i*16 + quad*4 + reg];

    #pragma unroll
    for (int j = 0; j < 4; j++) {
        const int c = blockN + wave_n*64 + j*16 + lrow;
        const float bbv = bbias[c];
        #pragma unroll
        for (int i = 0; i < 4; i++) {
            const int rl = wave_m*64 + i*16 + quad*4;
            const float* ep = embed + (size_t)(blockM + rl) * En + c;
            #pragma unroll
            for (int reg = 0; reg < 4; reg++)
                acc[i][j][reg] = wr[i][reg] * fast_tanh(acc[i][j][reg] + bbv)
                               * ep[(size_t)reg * En];
        }
    }

    // ---- per-wave column totals (64 rows each) -> redbuf ----
    float colsum[4];
    #pragma unroll
    for (int j = 0; j < 4; j++) {
        float s = 0.f;
        #pragma unroll
        for (int i = 0; i < 4; i++)
            #pragma unroll
            for (int reg = 0; reg < 4; reg++) s += acc[i][j][reg];
        s += __shfl_xor(s, 16, 64);
        s += __shfl_xor(s, 32, 64);
        colsum[j] = s;
    }
    if (lane < 16) {
        #pragma unroll
        for (int j = 0; j < 4; j++) redbuf[wq*64 + j*16 + lane] = colsum[j];
    }
    __syncthreads();

    // ---- cross-chunk chain: wait pred, read offsets, publish our prefix ----
    const int sidx = g * NCH + cidx;
    float* myinc = incb + (size_t)sidx * 128;
    if (cidx > 0) {
        if (tid == 0) {
            while (__hip_atomic_load(&status[sidx - 1], __ATOMIC_ACQUIRE,
                                     __HIP_MEMORY_SCOPE_AGENT) == 0u)
                __builtin_amdgcn_s_sleep(2);
        }
        __syncthreads();
    }
    if (tid < 128) {
        float off = 0.f;
        if (cidx > 0)
            off = __hip_atomic_load(incb + (size_t)(sidx - 1) * 128 + tid,
                                    __ATOMIC_RELAXED, __HIP_MEMORY_SCOPE_AGENT);
        offsbuf[tid] = off;
        const float tot = redbuf[tid] + redbuf[128 + tid];   // m0 + m1 halves
        __hip_atomic_store(myinc + tid, off + tot,
                           __ATOMIC_RELAXED, __HIP_MEMORY_SCOPE_AGENT);
    }
    __threadfence();
    __syncthreads();
    if (tid == 0)
        __hip_atomic_store(&status[sidx], 1u, __ATOMIC_RELEASE, __HIP_MEMORY_SCOPE_AGENT);

    // ---- in-register row cumsum + divide by cw + single coherent store ----
    float drcp[4][4];
    #pragma unroll
    for (int i = 0; i < 4; i++)
        #pragma unroll
        for (int reg = 0; reg < 4; reg++)
            drcp[i][reg] = __builtin_amdgcn_rcpf(
                cwp[wave_m*64 + i*16 + quad*4 + reg] + 1e-10f);

    #pragma unroll
    for (int j = 0; j < 4; j++) {
        const int colh = wave_n*64 + j*16 + lrow;    // 0..127 within block
        const int c = blockN + colh;
        float base = offsbuf[colh];
        if (wave_m) base += redbuf[colh];            // add upper-half total
        #pragma unroll
        for (int i = 0; i < 4; i++) {
            // in-thread inclusive scan over reg (4 consecutive rows)
            const float p0 = acc[i][j][0];
            const float p1 = p0 + acc[i][j][1];
            const float p2 = p1 + acc[i][j][2];
            const float p3 = p2 + acc[i][j][3];
            // Hillis-Steele over the 4 quads (rows stride 4)
            float x = p3;
            float u = __shfl_up(x, 16, 64);
            if (quad >= 1) x += u;
            u = __shfl_up(x, 32, 64);
            if (quad >= 2) x += u;
            const float excl = x - p3;               // exclusive-quad prefix
            const float itot = __shfl(x, 48 + lrow, 64);  // this 16-row block total
            const int rl = wave_m*64 + i*16 + quad*4;
            float* op = outp + (size_t)(blockM + rl) * En + c;
            op[0]              = (base + excl + p0) * drcp[i][0];
            op[(size_t)En]     = (base + excl + p1) * drcp[i][1];
            op[(size_t)2*En]   = (base + excl + p2) * drcp[i][2];
            op[(size_t)3*En]   = (base + excl + p3) * drcp[i][3];
            base += itot;
        }
    }
}

extern "C" void kernel_launch(void* const* d_in, const int* in_sizes, int n_in,
                              void* d_out, int out_size, void* d_ws, size_t ws_size,
                              hipStream_t stream) {
    const float* alpha = (const float*)d_in[0];
    const float* beta  = (const float*)d_in[1];
    const float* embed = (const float*)d_in[2];
    const float* Wb    = (const float*)d_in[3];
    const float* bb    = (const float*)d_in[4];
    const float* Wa    = (const float*)d_in[5];
    const float* ba    = (const float*)d_in[6];
    float* out = (float*)d_out;

    // workspace layout (~2 MB)
    unsigned short* wb_bf = (unsigned short*)d_ws;             // En*Hn bf16 (0.5 MB)
    float* wbuf     = (float*)(wb_bf + (size_t)En * Hn);       // Mn
    float* cwbuf    = wbuf + Mn;                               // Mn
    float* incb     = cwbuf + Mn;                              // NG*NCH*128 (1 MB)
    unsigned* status  = (unsigned*)(incb + (size_t)NG * NCH * 128); // NG*NCH
    unsigned* counter = status + NG * NCH;                     // 1

    k_init<<<(NG * NCH + 1 + 255) / 256, 256, 0, stream>>>(status, NG * NCH + 1);
    k_conv<<<(En * Hn / 8 + 255) / 256, 256, 0, stream>>>(Wb, wb_bf, En * Hn / 8);
    k_w<<<Mn / 4, 256, 0, stream>>>(alpha, Wa, ba, wbuf);
    k_scan_w<<<Bn, 64, 0, stream>>>(wbuf, cwbuf);
    k_gemm3<<<NBLOCKS, 256, 0, stream>>>(beta, wb_bf, bb, wbuf, cwbuf, embed,
                                         out, incb, status, counter);
}